// Round 30
// baseline (40.306 us; speedup 1.0000x reference)
//
#include <hip/hip_runtime.h>

// LNCC loss: I,J [16,1,768,768] f32 -> out [16] f32
// R30 = R22 structure with SEG 12->16: amortize the per-task fixed cost
// (8 warmup rows + 6 preload rows) over 16 output rows instead of 12.
// R22's per-task loads = 32 rows/12 out (2.67x); here 40/16 (2.5x) and 25%
// fewer tasks -> ~6-8% fewer total loads + fewer warmups. Both I and O now
// rotate through 3 buffers (IA/IB/IC, OA/OB/OC) across 8 chunks — peak live
// buffers unchanged (6 x 16B = 96 regs), so VGPR stays under the 128 cliff
// (R13/R15/R16's SEG=16 attempts were all cap-confounded; this is the clean
// test). Uniform depth-2 on both streams, same as R22.
// Gates: VGPR<=126 AND WRITE_SIZE<1KB, else revert to R22 as final.

constexpr int BATCH = 16;
constexpr int H = 768;
constexpr int W = 768;
constexpr float INV_WS = 1.0f / 81.0f;
constexpr float EPS = 3.0590232050182579e-07f;   // exp(-15)

constexpr int SEG = 16;                   // output rows per wave task
constexpr int NSEG = H / SEG;             // 48
constexpr int BANDW = 248;                // output cols per band (bands 0-2)
constexpr int NTHREADS = 256;             // 4 waves
constexpr int PPI = 150;                  // partials per image: 48*3 main + 6 band3

#define F4ADD(a, u)    { a.x += u.x; a.y += u.y; a.z += u.z; a.w += u.w; }
#define F4SUB(a, u)    { a.x -= u.x; a.y -= u.y; a.z -= u.z; a.w -= u.w; }
#define F4FMA(a, u, v) { a.x = fmaf(u.x, v.x, a.x); a.y = fmaf(u.y, v.y, a.y); \
                         a.z = fmaf(u.z, v.z, a.z); a.w = fmaf(u.w, v.w, a.w); }
#define F4FMS(a, u, v) { a.x = fmaf(u.x, -v.x, a.x); a.y = fmaf(u.y, -v.y, a.y); \
                         a.z = fmaf(u.z, -v.z, a.z); a.w = fmaf(u.w, -v.w, a.w); }

// h[e] = sum of cs cols [c0+e, c0+e+8]; output col = c0+4+e
#define HSUM_SHFL(c, h)                                                   \
    {                                                                     \
        const float s3 = c.w;                                             \
        const float s2 = c.w + c.z;                                       \
        const float s1 = s2 + c.y;                                        \
        const float s0 = s1 + c.x;          /* own total */               \
        const float p1 = c.x + c.y;                                       \
        const float p2 = p1 + c.z;                                        \
        const float pn = __shfl_down(s0, 1, 64);                          \
        const float q0 = __shfl_down(c.x, 2, 64);                         \
        const float q1 = __shfl_down(p1, 2, 64);                          \
        const float q2 = __shfl_down(p2, 2, 64);                          \
        const float q3 = __shfl_down(s0, 2, 64);                          \
        h[0] = s0 + pn + q0;                                              \
        h[1] = s1 + pn + q1;                                              \
        h[2] = s2 + pn + q2;                                              \
        h[3] = s3 + pn + q3;                                              \
    }

// load 2 rows (rbase, rbase+1) PRE-MASKED (addr clamped, scaled by row-mask*fm)
#define LD2(NI, NJ, rbase)                                                \
    {                                                                     \
        _Pragma("unroll")                                                 \
        for (int k = 0; k < 2; ++k) {                                     \
            const int rr = (rbase) + k;                                   \
            const int rc = min(max(rr, 0), H - 1);                        \
            const float mk = (rr >= 0 && rr < H) ? fm : 0.0f;             \
            float4 ti = *(const float4*)(Ib + (size_t)rc * W + ca);       \
            float4 tj = *(const float4*)(Jb + (size_t)rc * W + ca);       \
            ti.x *= mk; ti.y *= mk; ti.z *= mk; ti.w *= mk;               \
            tj.x *= mk; tj.y *= mk; tj.z *= mk; tj.w *= mk;               \
            NI[k] = ti; NJ[k] = tj;                                       \
        }                                                                 \
    }

// compute 2 output rows from pre-masked in-batch (VI,VJ) and out-batch (OI,OJ)
#define CHUNK(VI, VJ, OI, OJ)                                             \
    _Pragma("unroll")                                                     \
    for (int k = 0; k < 2; ++k) {                                         \
        F4ADD(cs0, VI[k]) F4ADD(cs1, VJ[k])                               \
        F4FMA(cs2, VI[k], VI[k]) F4FMA(cs3, VJ[k], VJ[k])                 \
        F4FMA(cs4, VI[k], VJ[k])                                          \
        float hI[4], hJ[4], hII[4], hJJ[4], hIJ[4];                       \
        HSUM_SHFL(cs0, hI)                                                \
        HSUM_SHFL(cs1, hJ)                                                \
        HSUM_SHFL(cs2, hII)                                               \
        HSUM_SHFL(cs3, hJJ)                                               \
        HSUM_SHFL(cs4, hIJ)                                               \
        float rowsum = 0.0f;                                              \
        _Pragma("unroll")                                                 \
        for (int e = 0; e < 4; ++e) {                                     \
            const float u = -hI[e] * INV_WS;                              \
            const float cross = fmaf(u, hJ[e], hIJ[e]);                   \
            const float Ivar  = fmaf(u, hI[e], hII[e]);                   \
            const float Jvar  = fmaf(-hJ[e] * INV_WS, hJ[e], hJJ[e]);     \
            float prod = Ivar * Jvar;                                     \
            float num  = cross * cross;                                   \
            if (!(prod > EPS)) { prod = 1.0f; num = 1.0f; }               \
            float inv_;                                                   \
            asm("v_rcp_f32 %0, %1" : "=v"(inv_) : "v"(prod + EPS));       \
            rowsum = fmaf(num, inv_, rowsum);                             \
        }                                                                 \
        accum += live ? rowsum : 0.0f;                                    \
        F4SUB(cs0, OI[k]) F4SUB(cs1, OJ[k])                               \
        F4FMS(cs2, OI[k], OI[k]) F4FMS(cs3, OJ[k], OJ[k])                 \
        F4FMS(cs4, OI[k], OJ[k])                                          \
    }

__launch_bounds__(NTHREADS, 2)
__global__ void lncc_s16(const float* __restrict__ gI, const float* __restrict__ gJ,
                         float* __restrict__ part)
{
    const int lane = threadIdx.x & 63;
    const int band = threadIdx.x >> 6;                   // 0..3
    const int seg  = blockIdx.x;                         // 0..47
    const int b    = blockIdx.y;

    int r0, c0;
    bool live;
    if (band < 3) {
        r0 = seg * SEG;
        c0 = band * BANDW - 4 + 4 * lane;                // own cs base col
        live = (lane <= 61);                             // bands 0-2 fully live
    } else {
        if (seg & 7) return;                             // wave-uniform exit
        const int rch = lane >> 3;                       // row-chunk 0..7
        const int cg  = lane & 7;                        // col-group 0..7
        r0 = (seg + rch) * SEG;                          // per-lane segment
        c0 = 740 + 4 * cg;                               // cs cols 740..771
        live = (cg <= 5);                                // outputs 744..767
    }
    const float fm = (c0 >= 0 && c0 + 3 < W) ? 1.0f : 0.0f;
    const int ca   = min(max(c0, 0), W - 4);             // 16B-aligned clamp

    const float* __restrict__ Ib = gI + (size_t)b * (H * W);
    const float* __restrict__ Jb = gJ + (size_t)b * (H * W);

    float4 cs0 = {0,0,0,0}, cs1 = {0,0,0,0}, cs2 = {0,0,0,0},
           cs3 = {0,0,0,0}, cs4 = {0,0,0,0};

    // ---- warm-up: 4 pre-masked 2-row chunks (rows r0-4 .. r0+3) ----
    float4 W0i[2], W0j[2], W1i[2], W1j[2], W2i[2], W2j[2], W3i[2], W3j[2];
    LD2(W0i, W0j, r0 - 4)
    LD2(W1i, W1j, r0 - 2)
    LD2(W2i, W2j, r0)
    LD2(W3i, W3j, r0 + 2)

    // ---- pipeline preload: in-chunks 0,1 (depth 2) + out-chunk 0 ----
    float4 IAi[2], IAj[2], IBi[2], IBj[2], ICi[2], ICj[2];
    float4 OAi[2], OAj[2], OBi[2], OBj[2], OCi[2], OCj[2];
    LD2(IAi, IAj, r0 + 4)
    LD2(IBi, IBj, r0 + 6)
    LD2(OAi, OAj, r0 - 4)

    // warm-up accumulate (~700 cy) covers the preload latency
#define WACC(WI, WJ)                                                      \
    _Pragma("unroll")                                                     \
    for (int k = 0; k < 2; ++k) {                                         \
        F4ADD(cs0, WI[k]) F4ADD(cs1, WJ[k])                               \
        F4FMA(cs2, WI[k], WI[k]) F4FMA(cs3, WJ[k], WJ[k])                 \
        F4FMA(cs4, WI[k], WJ[k])                                          \
    }
    WACC(W0i, W0j) WACC(W1i, W1j) WACC(W2i, W2j) WACC(W3i, W3j)
#undef WACC

    float accum = 0.0f;

    // ---- 8 pipelined chunks of 2 rows (SEG = 16) ----
    // chunk c: rows r0+2c..+1; in-batch = rows r0+2c+4 (issued 2 chunks
    // ahead, IA/IB/IC rotation); out-batch = rows r0+2c-4 (issued 2 chunks
    // ahead, OA/OB/OC rotation). Every reload happens after its buffer's
    // previous consumer chunk.
    LD2(ICi, ICj, r0 + 8)   LD2(OBi, OBj, r0 - 2)
                            LD2(OCi, OCj, r0)       CHUNK(IAi, IAj, OAi, OAj)
    LD2(IAi, IAj, r0 + 10)  LD2(OAi, OAj, r0 + 2)   CHUNK(IBi, IBj, OBi, OBj)
    LD2(IBi, IBj, r0 + 12)  LD2(OBi, OBj, r0 + 4)   CHUNK(ICi, ICj, OCi, OCj)
    LD2(ICi, ICj, r0 + 14)  LD2(OCi, OCj, r0 + 6)   CHUNK(IAi, IAj, OAi, OAj)
    LD2(IAi, IAj, r0 + 16)  LD2(OAi, OAj, r0 + 8)   CHUNK(IBi, IBj, OBi, OBj)
    LD2(IBi, IBj, r0 + 18)  LD2(OBi, OBj, r0 + 10)  CHUNK(ICi, ICj, OCi, OCj)
                                                    CHUNK(IAi, IAj, OAi, OAj)
                                                    CHUNK(IBi, IBj, OBi, OBj)

    // ---- wave reduce -> one partial-store per wave (no LDS, no barrier) ----
    #pragma unroll
    for (int off = 32; off > 0; off >>= 1)
        accum += __shfl_xor(accum, off, 64);
    if (lane == 0) {
        if (band < 3)
            part[b * PPI + seg * 3 + band] = accum;      // slots 0..143
        else
            part[b * PPI + 144 + (seg >> 3)] = accum;    // slots 144..149
    }
}

// one wave per batch image: reduce 150 wave-partials, write final loss
__global__ void finalize2(const float* __restrict__ part, float* __restrict__ out) {
    const int b = threadIdx.y;              // 0..15 (one wave each)
    const int x = threadIdx.x;              // 0..63
    const int base = b * PPI;
    float v = part[base + x] + part[base + 64 + x];
    if (x < 22) v += part[base + 128 + x];
    #pragma unroll
    for (int off = 32; off > 0; off >>= 1)
        v += __shfl_xor(v, off, 64);
    if (x == 0)
        out[b] = 1.0f - v * (1.0f / (float)(H * W));
}

extern "C" void kernel_launch(void* const* d_in, const int* in_sizes, int n_in,
                              void* d_out, int out_size, void* d_ws, size_t ws_size,
                              hipStream_t stream) {
    const float* I = (const float*)d_in[0];
    const float* J = (const float*)d_in[1];
    float* out  = (float*)d_out;
    float* part = (float*)d_ws;             // 16*150 floats, all written each launch

    dim3 grid(NSEG, BATCH);   // 48 x 16 = 768 blocks = exactly 3/CU; 2400 working waves
    lncc_s16<<<grid, NTHREADS, 0, stream>>>(I, J, part);

    finalize2<<<1, dim3(64, BATCH), 0, stream>>>(part, out);
}